// Round 1
// baseline (1090.720 us; speedup 1.0000x reference)
//
#include <hip/hip_runtime.h>
#include <stdint.h>

// Problem constants (match reference)
#define Bb   32
#define Nn   64
#define Hh   32
#define Dd   20
#define Ee   64
#define NP1  65
#define KK   (Dd * Ee)   // 1280
#define NUM_SPATIAL 512

#define KC   32          // K-chunk staged to LDS (32 floats = 128 B per row)
#define NCH  (KK / KC)   // 40 chunks

// ---------------------------------------------------------------------------
// K1: C[k][g], k = d*64+e:  C = sum_h W_edge[h][e] * W3[d][h][g]
// W3[d][h][g] = edge_dis_weight[(d*32+h)*32+g]
// ---------------------------------------------------------------------------
__global__ void build_C(const float* __restrict__ W_edge,
                        const float* __restrict__ edw,
                        float* __restrict__ C) {
    int idx = blockIdx.x * 256 + threadIdx.x;   // over D*E*H = 40960
    if (idx >= Dd * Ee * Hh) return;
    int g = idx & 31;
    int e = (idx >> 5) & 63;
    int d = idx >> 11;
    float s = 0.f;
#pragma unroll
    for (int h = 0; h < Hh; ++h)
        s += W_edge[h * Ee + e] * edw[(d * Hh + h) * Hh + g];
    C[idx] = s;
}

// ---------------------------------------------------------------------------
// K2: interior output  O[b][g][1+i][1+j] = 2*ab[b][1+i][1+j]
//        + spatial_emb[spos[b][i][j]][g] + (sum_k X[b,i,j,k]*C[k,g]) / sp
//
// Decomposition: block = 256 threads = 4 waves, owns 256 positions (4 i-rows).
// Lane owns ONE position (pos = threadIdx.x) and ALL 32 g -> acc[32].
//   - X row chunk lives in LDS: linear [256][KC] floats, XOR-swizzled at 16B
//     granularity: slot s holds k4 = s ^ (pos&7)  (conflict-free ds_read_b128,
//     and global_load_lds-compatible: LDS dest linear, swizzle pre-applied to
//     the per-lane GLOBAL source address).
//   - C[k][0..31] is wave-uniform -> scalar loads (s_load_dwordx16).
//   - Double-buffered staging (2 x 32 KB LDS), stage issued before compute,
//     one barrier per chunk.
// ---------------------------------------------------------------------------
__global__ __launch_bounds__(256, 2) void main_kernel(
    const float* __restrict__ ab,      // [B][65][65]
    const int*   __restrict__ spos,    // [B][64][64]
    const float* __restrict__ X,       // [B][64][64][20][64] = [.][.][.][1280]
    const float* __restrict__ C,       // [1280][32]
    const float* __restrict__ semb,    // [513][32]
    float* __restrict__ O)             // [B][32][65][65]
{
    __shared__ float Xs[2 * 256 * KC];            // 2 x 32 KB

    const int t   = threadIdx.x;
    const int l   = t & 63;
    const int wid = t >> 6;
    const int b   = blockIdx.x >> 4;              // 0..31
    const int i0  = (blockIdx.x & 15) * 4;        // 0,4,...,60

    const float* __restrict__ Xblk = X + (size_t)(b * Nn + i0) * Nn * KK; // 256 rows x 1280

    // ---- staging source (per-lane; constant across chunks except +kc) ----
    // wave w instr ii covers rows [w*64 + ii*8, +8), 8 slots (16B) per row.
    // lane l -> row = w*64 + ii*8 + (l>>3), slot s = l&7, holds k4 = s ^ (row&7)
    // row&7 == (l>>3)&7 here, so k4src is ii/w-independent.
    const int prow0 = wid * 64 + (l >> 3);
    const int k4src = (l & 7) ^ ((l >> 3) & 7);
    const float* gsrc0 = Xblk + (size_t)prow0 * KK + k4src * 4;

    // wave-uniform LDS float offset of this wave's staging region
    const int ldswave = __builtin_amdgcn_readfirstlane(wid * (64 * KC));

    float acc[32];
#pragma unroll
    for (int g = 0; g < 32; ++g) acc[g] = 0.f;

    // ---- prologue: stage chunk 0 into buffer 0 ----
#pragma unroll
    for (int ii = 0; ii < 8; ++ii) {
        __builtin_amdgcn_global_load_lds(
            (const uint32_t*)(gsrc0 + ii * (8 * KK)),
            (uint32_t*)(Xs + ldswave + ii * 256),
            16, 0, 0);
    }
    __syncthreads();

    int buf = 0;
    for (int c = 0; c < NCH; ++c) {
        const int kc = c * KC;

        // issue next-chunk staging first (flies during compute)
        if (c + 1 < NCH) {
            const float* gs = gsrc0 + (kc + KC);
            float* ldst = Xs + (buf ^ 1) * (256 * KC) + ldswave;
#pragma unroll
            for (int ii = 0; ii < 8; ++ii) {
                __builtin_amdgcn_global_load_lds(
                    (const uint32_t*)(gs + ii * (8 * KK)),
                    (uint32_t*)(ldst + ii * 256),
                    16, 0, 0);
            }
        }

        // compute current chunk: 8 x (ds_read_b128 + 128 FMA)
        const float* Cc = C + (size_t)kc * Hh;                      // uniform
        const float* rb = Xs + buf * (256 * KC) + (size_t)t * KC;   // my row
#pragma unroll
        for (int k4 = 0; k4 < 8; ++k4) {
            const float4 xv = *(const float4*)(rb + ((k4 ^ (l & 7)) << 2));
            const float xk[4] = {xv.x, xv.y, xv.z, xv.w};
#pragma unroll
            for (int kk = 0; kk < 4; ++kk) {
                const float x = xk[kk];
                const float* Cr = Cc + (k4 * 4 + kk) * Hh;          // uniform -> s_load
#pragma unroll
                for (int g = 0; g < 32; ++g)
                    acc[g] = fmaf(x, Cr[g], acc[g]);
            }
        }

        __syncthreads();   // staged chunk c+1 complete; all reads of buf done
        buf ^= 1;
    }

    // ---- epilogue ----
    const int i = i0 + wid;        // pos = t: i-row = t>>6, j = t&63
    const int j = l;
    const int spraw = spos[(b * Nn + i) * Nn + j];
    int sp = (spraw == 0) ? 1 : spraw;
    sp = (sp > 1) ? sp - 1 : sp;
    sp = (sp > Dd) ? Dd : sp;
    const float inv   = 1.f / (float)sp;
    const float base2 = 2.f * ab[((size_t)b * NP1 + (1 + i)) * NP1 + (1 + j)];

    const float4* srow = (const float4*)(semb + (size_t)spraw * Hh);
#pragma unroll
    for (int q = 0; q < 8; ++q) {
        const float4 sv = srow[q];
        const float s4[4] = {sv.x, sv.y, sv.z, sv.w};
#pragma unroll
        for (int r = 0; r < 4; ++r) {
            const int g = q * 4 + r;
            O[(((size_t)b * Hh + g) * NP1 + (1 + i)) * NP1 + (1 + j)] =
                fmaf(acc[g], inv, s4[r] + base2);
        }
    }
}

// ---------------------------------------------------------------------------
// K3: border — i==0 row (all j) and j==0 col (i>=1):  O = 2*ab + vd[h]
// ---------------------------------------------------------------------------
__global__ void border_kernel(const float* __restrict__ ab,
                              const float* __restrict__ vd,
                              float* __restrict__ O) {
    int idx = blockIdx.x * 256 + threadIdx.x;   // B*H*129
    if (idx >= Bb * Hh * 129) return;
    int e  = idx % 129;
    int bh = idx / 129;
    int h  = bh & 31;
    int b  = bh >> 5;
    int i, j;
    if (e < 65) { i = 0; j = e; } else { i = e - 64; j = 0; }
    float v = 2.f * ab[((size_t)b * NP1 + i) * NP1 + j] + vd[h];
    O[(((size_t)b * Hh + h) * NP1 + i) * NP1 + j] = v;
}

// ---------------------------------------------------------------------------
extern "C" void kernel_launch(void* const* d_in, const int* in_sizes, int n_in,
                              void* d_out, int out_size, void* d_ws, size_t ws_size,
                              hipStream_t stream) {
    // setup_inputs() order:
    // 0 node_features (unused), 1 attn_bias, 2 spatial_pos, 3 edge_input,
    // 4 attn_edge_type (unused), 5 W_edge, 6 spatial_emb, 7 vd_weight,
    // 8 edge_dis_weight
    const float* ab   = (const float*)d_in[1];
    const int*   spos = (const int*)  d_in[2];
    const float* X    = (const float*)d_in[3];
    const float* We   = (const float*)d_in[5];
    const float* semb = (const float*)d_in[6];
    const float* vd   = (const float*)d_in[7];
    const float* edw  = (const float*)d_in[8];
    float* O = (float*)d_out;
    float* C = (float*)d_ws;   // 40960 floats = 160 KB

    build_C<<<(Dd * Ee * Hh + 255) / 256, 256, 0, stream>>>(We, edw, C);
    main_kernel<<<Bb * 16, 256, 0, stream>>>(ab, spos, X, C, semb, O);
    border_kernel<<<(Bb * Hh * 129 + 255) / 256, 256, 0, stream>>>(ab, vd, O);
}

// Round 2
// 960.058 us; speedup vs baseline: 1.1361x; 1.1361x over previous
//
#include <hip/hip_runtime.h>
#include <stdint.h>

// Problem constants (match reference)
#define Bb   32
#define Nn   64
#define Hh   32
#define Dd   20
#define Ee   64
#define NP1  65
#define KK   (Dd * Ee)   // 1280
#define NUM_SPATIAL 512

// ---------------------------------------------------------------------------
// K1: C[k][g], k = d*64+e:  C = sum_h W_edge[h][e] * W3[d][h][g]
// W3[d][h][g] = edge_dis_weight[(d*32+h)*32+g]
// ---------------------------------------------------------------------------
__global__ void build_C(const float* __restrict__ W_edge,
                        const float* __restrict__ edw,
                        float* __restrict__ C) {
    int idx = blockIdx.x * 256 + threadIdx.x;   // over D*E*H = 40960
    if (idx >= Dd * Ee * Hh) return;
    int g = idx & 31;
    int e = (idx >> 5) & 63;
    int d = idx >> 11;
    float s = 0.f;
#pragma unroll
    for (int h = 0; h < Hh; ++h)
        s += W_edge[h * Ee + e] * edw[(d * Hh + h) * Hh + g];
    C[idx] = s;
}

// ---------------------------------------------------------------------------
// K2: interior output  O[b][g][1+i][1+j] = 2*ab[b][1+i][1+j]
//        + spatial_emb[spos[b][i][j]][g] + (sum_k X[b,i,j,k]*C[k,g]) / sp
//
// Streaming design (no LDS, no barriers):
//   - lane owns ONE position (b,i,j); its X row (1280 floats) is contiguous
//     in global -> per-lane float4 stream. 64B granules fully consumed within
//     4 consecutive k4 steps via L1 (64 live lines/wave << 256-line L1).
//   - C[k][0..31] wave-uniform -> scalar (s_load) path, L2-resident.
//   - manual 8-deep register rotation: 8 loads in flight under 1024 FMAs
//     (~2048 cyc) >> ~900 cyc HBM latency. All array indexing static.
// ---------------------------------------------------------------------------
__global__ __launch_bounds__(256) void main_kernel(
    const float* __restrict__ ab,      // [B][65][65]
    const int*   __restrict__ spos,    // [B][64][64]
    const float* __restrict__ X,       // [B][64][64][1280]
    const float* __restrict__ C,       // [1280][32]
    const float* __restrict__ semb,    // [513][32]
    float* __restrict__ O)             // [B][32][65][65]
{
    const int t  = threadIdx.x;
    const int b  = blockIdx.x >> 4;          // 0..31
    const int i0 = (blockIdx.x & 15) * 4;    // 0,4,...,60
    const int i  = i0 + (t >> 6);
    const int j  = t & 63;

    const float4* __restrict__ Xrow =
        (const float4*)(X + (size_t)((b * Nn + i) * Nn + j) * KK);  // 320 float4

    float acc[32];
#pragma unroll
    for (int g = 0; g < 32; ++g) acc[g] = 0.f;

    // prologue: fill 8-deep pipeline
    float4 buf[8];
#pragma unroll
    for (int u = 0; u < 8; ++u) buf[u] = Xrow[u];

    for (int kb = 0; kb < KK / 32; ++kb) {    // 40 macro-steps of 32 k
        // issue next block's 8 loads early (clamped on last iter; redundant
        // loads hit L1)
        const int kn = (kb + 1 < KK / 32) ? kb + 1 : kb;
        float4 nbuf[8];
#pragma unroll
        for (int u = 0; u < 8; ++u) nbuf[u] = Xrow[kn * 8 + u];

        const float* __restrict__ Cb = C + (size_t)kb * 32 * Hh;  // uniform
#pragma unroll
        for (int u = 0; u < 8; ++u) {
            const float xk[4] = {buf[u].x, buf[u].y, buf[u].z, buf[u].w};
#pragma unroll
            for (int kk = 0; kk < 4; ++kk) {
                const float x = xk[kk];
                const float* __restrict__ Cr = Cb + (u * 4 + kk) * Hh;  // uniform -> s_load
#pragma unroll
                for (int g = 0; g < 32; ++g)
                    acc[g] = fmaf(x, Cr[g], acc[g]);
            }
        }

#pragma unroll
        for (int u = 0; u < 8; ++u) buf[u] = nbuf[u];
    }

    // ---- epilogue ----
    const int spraw = spos[(b * Nn + i) * Nn + j];
    int sp = (spraw == 0) ? 1 : spraw;
    sp = (sp > 1) ? sp - 1 : sp;
    sp = (sp > Dd) ? Dd : sp;
    const float inv   = 1.f / (float)sp;
    const float base2 = 2.f * ab[((size_t)b * NP1 + (1 + i)) * NP1 + (1 + j)];

    const float4* srow = (const float4*)(semb + (size_t)spraw * Hh);
#pragma unroll
    for (int q = 0; q < 8; ++q) {
        const float4 sv = srow[q];
        const float s4[4] = {sv.x, sv.y, sv.z, sv.w};
#pragma unroll
        for (int r = 0; r < 4; ++r) {
            const int g = q * 4 + r;
            O[(((size_t)b * Hh + g) * NP1 + (1 + i)) * NP1 + (1 + j)] =
                fmaf(acc[g], inv, s4[r] + base2);
        }
    }
}

// ---------------------------------------------------------------------------
// K3: border — i==0 row (all j) and j==0 col (i>=1):  O = 2*ab + vd[h]
// ---------------------------------------------------------------------------
__global__ void border_kernel(const float* __restrict__ ab,
                              const float* __restrict__ vd,
                              float* __restrict__ O) {
    int idx = blockIdx.x * 256 + threadIdx.x;   // B*H*129
    if (idx >= Bb * Hh * 129) return;
    int e  = idx % 129;
    int bh = idx / 129;
    int h  = bh & 31;
    int b  = bh >> 5;
    int i, j;
    if (e < 65) { i = 0; j = e; } else { i = e - 64; j = 0; }
    float v = 2.f * ab[((size_t)b * NP1 + i) * NP1 + j] + vd[h];
    O[(((size_t)b * Hh + h) * NP1 + i) * NP1 + j] = v;
}

// ---------------------------------------------------------------------------
extern "C" void kernel_launch(void* const* d_in, const int* in_sizes, int n_in,
                              void* d_out, int out_size, void* d_ws, size_t ws_size,
                              hipStream_t stream) {
    // setup_inputs() order:
    // 0 node_features (unused), 1 attn_bias, 2 spatial_pos, 3 edge_input,
    // 4 attn_edge_type (unused), 5 W_edge, 6 spatial_emb, 7 vd_weight,
    // 8 edge_dis_weight
    const float* ab   = (const float*)d_in[1];
    const int*   spos = (const int*)  d_in[2];
    const float* X    = (const float*)d_in[3];
    const float* We   = (const float*)d_in[5];
    const float* semb = (const float*)d_in[6];
    const float* vd   = (const float*)d_in[7];
    const float* edw  = (const float*)d_in[8];
    float* O = (float*)d_out;
    float* C = (float*)d_ws;   // 40960 floats = 160 KB

    build_C<<<(Dd * Ee * Hh + 255) / 256, 256, 0, stream>>>(We, edw, C);
    main_kernel<<<Bb * 16, 256, 0, stream>>>(ab, spos, X, C, semb, O);
    border_kernel<<<(Bb * Hh * 129 + 255) / 256, 256, 0, stream>>>(ab, vd, O);
}